// Round 6
// baseline (673.484 us; speedup 1.0000x reference)
//
#include <hip/hip_runtime.h>
#include <hip/hip_bf16.h>

// ScaleDotProduct attention fwd, MI355X gfx950.  B=2 H=16 S=2048 D=64.
// Dtypes (locked r5): Q/K/V f32, output f32, mask u8-or-i32 (runtime probe).
//
// r16: EXACTLY-ONCE restructure.  r10 (72us) relied on 32 blocks/head
// re-reading K/V through L2 in self-synchronized lockstep (FETCH 79MB ~=
// ideal); r11's faster compute broke the sync -> L2 collapse (r13/14/15:
// 330-710MB, 185-208us) regardless of blockIdx mapping.  Fix: bound the
// traffic BY CONSTRUCTION.  One block = 256 q-rows x full K/V sweep for
// one head.  Grid = 32 heads x 8 q-chunks = 256 blocks (1/CU), 8 waves x
// 32 q-rows (2 subtiles).  Chip-wide staging = 256 x 512KB = 134MB WORST
// case (each block reads each K/V byte once); grid x=bh groups same-head
// blocks per XCD for opportunistic L2 sharing (best ~52MB).  No reliance
// on inter-block timing.  No setprio (lockstep-neutral).
// Kept from r11-r13 (verified: bank conflicts 8.4M->0; PV MFMA cyc halved):
//  * sigma-permuted QK^T: K-frag lane ln loads key row 32T+(ln>>2)*8+4u+
//    (ln&3) for subtile t=2T+u -> two St subtiles concat into the A-frag
//    [m=ln][k=quad*8+j] of mfma_f32_16x16x32_f16; PV = 8x K=32 mfma.
//  * V B-frags 8x ds_read_b128, conflict-free (8 lanes x 8 cols x 8 phases).
//  * K swizzle fsw(r)=(r&3)|((r>>3)&1)<<2; READ key = fswf(sigma(ln)) =
//    (ln&3)|(((ln>>2)&1)<<2)  [sigma's bit3 = ln's bit2].
//  * mask folded into St accumulator INIT (-512 bias; exp2 -> exact 0).
//  * P pack via v_cvt_pkrtz pairs; wm loads pipelined 1 tile ahead;
//    LDS read offsets precomputed outside kv-loop.
// Layouts (m89/m120-verified + guide SS3, dtype-independent):
//   16x16 C/D: col=lane&15, row=quad*4+reg
//   16x16x32 A: [m=ln][k=quad*8+j]  B: [k=quad*8+j][n=ln]
// Fixed-max exp2-domain softmax (r7): p=exp2(s*log2e/8); masked p=0;
// l==0 -> 0 reproduces nan_to_num.

#define S_LEN 2048
#define D_DIM 64
#define BH    32
#define QCH   256            // q rows per block
#define BN    64             // kv rows per tile
#define PST   72
#define QSCALE 0.1803368801f   // 0.125 * log2(e)

typedef __bf16    bf16_t;
typedef _Float16  f16_t;
typedef bf16_t bf16x8 __attribute__((ext_vector_type(8)));
typedef f16_t  f16x2  __attribute__((ext_vector_type(2)));
typedef f16_t  f16x4  __attribute__((ext_vector_type(4)));
typedef f16_t  f16x8  __attribute__((ext_vector_type(8)));
typedef float  f32x4  __attribute__((ext_vector_type(4)));
typedef unsigned char  u8;
typedef unsigned long long u64b;

__device__ __forceinline__ void load_lds16(const void* g, void* l) {
    __builtin_amdgcn_global_load_lds(
        (const __attribute__((address_space(1))) void*)g,
        (__attribute__((address_space(3))) void*)l, 16, 0, 0);
}

__device__ __forceinline__ f16x2 cvt_pk_f16(float a, float b) {
    return __builtin_bit_cast(f16x2, __builtin_amdgcn_cvt_pkrtz(a, b));
}

// swizzle group for K tiles: row bits that vary across the 16 lanes of one
// sigma-permuted A-frag load (bits 0,1 and 3).
__device__ __forceinline__ int fswf(int r) {
    return (r & 3) | (((r >> 3) & 1) << 2);
}

// ---- pre-pass 1: mask -> u64 bitmask (dtype probe: int32 dwords are {0,1};
// packed-bool dwords >1 w.p. ~7/8; 256 shared samples -> uniform verdict).
__global__ __launch_bounds__(256)
void mask_to_bits(const unsigned* __restrict__ M, u64b* __restrict__ bm)
{
    const int t = threadIdx.x;
    unsigned p = M[(t * 8179) & ((1 << 21) - 1)];
    const int is_u8 = __syncthreads_or(p > 1u);
    const int id = blockIdx.x * 256 + t;   // u64 index; 131072 total
    u64b w = 0;
    if (is_u8) {
        const uint4* src = (const uint4*)((const u8*)M + (size_t)id * 64);
        #pragma unroll
        for (int g = 0; g < 4; ++g) {
            uint4 x = src[g];
            const unsigned dw[4] = {x.x, x.y, x.z, x.w};
            #pragma unroll
            for (int q = 0; q < 4; ++q) {
                const unsigned v = dw[q];
                const int base = g * 16 + q * 4;
                if (v & 0x000000FFu) w |= 1ull << (base + 0);
                if (v & 0x0000FF00u) w |= 1ull << (base + 1);
                if (v & 0x00FF0000u) w |= 1ull << (base + 2);
                if (v & 0xFF000000u) w |= 1ull << (base + 3);
            }
        }
    } else {
        const uint4* src = (const uint4*)(M + (size_t)id * 64);
        #pragma unroll
        for (int g = 0; g < 16; ++g) {
            uint4 x = src[g];
            if (x.x) w |= 1ull << (g * 4 + 0);
            if (x.y) w |= 1ull << (g * 4 + 1);
            if (x.z) w |= 1ull << (g * 4 + 2);
            if (x.w) w |= 1ull << (g * 4 + 3);
        }
    }
    bm[id] = w;
}

// ---- pre-pass 2: K -> bf16, 16B groups XOR-swizzled (fswf) per 64-elem row
__global__ __launch_bounds__(256)
void k_prep(const float* __restrict__ K, bf16_t* __restrict__ Kb)
{
    const size_t i = ((size_t)blockIdx.x * 256 + threadIdx.x) * 8;
    float4 a = *(const float4*)(K + i);
    float4 b = *(const float4*)(K + i + 4);
    bf16x8 w;
    w[0]=(bf16_t)a.x; w[1]=(bf16_t)a.y; w[2]=(bf16_t)a.z; w[3]=(bf16_t)a.w;
    w[4]=(bf16_t)b.x; w[5]=(bf16_t)b.y; w[6]=(bf16_t)b.z; w[7]=(bf16_t)b.w;
    const size_t r = i >> 6;
    const int    g = (int)((i & 63) >> 3);
    *(bf16x8*)(Kb + r * 64 + ((g ^ fswf((int)(r & 63))) * 8)) = w;
}

// ---- pre-pass 3: V f32 [bh][s][d] -> Vt f16 tile-images
// [bh][kbt][d][k_in64], 16B-group XOR swizzle (g^(d&7)).
__global__ __launch_bounds__(256)
void v_transpose(const float* __restrict__ V, f16_t* __restrict__ Vt)
{
    __shared__ f16_t T[128][PST];
    const int t  = threadIdx.x;
    const int sc = blockIdx.x;    // 16 chunks of 128 s
    const int bh = blockIdx.y;    // 32
    const float* Vh = V + ((size_t)bh * S_LEN + sc * 128) * D_DIM;
    #pragma unroll
    for (int it = 0; it < 4; ++it) {
        const int row = it * 32 + (t >> 3);
        const int c8  = (t & 7) * 8;
        float4 a = *(const float4*)(Vh + row * D_DIM + c8);
        float4 b = *(const float4*)(Vh + row * D_DIM + c8 + 4);
        f16_t* d = &T[row][c8];
        d[0]=(f16_t)a.x; d[1]=(f16_t)a.y; d[2]=(f16_t)a.z; d[3]=(f16_t)a.w;
        d[4]=(f16_t)b.x; d[5]=(f16_t)b.y; d[6]=(f16_t)b.z; d[7]=(f16_t)b.w;
    }
    __syncthreads();
    const int d = t >> 2;
    #pragma unroll
    for (int g = 0; g < 4; ++g) {
        const int s_off = (t & 3) * 32 + g * 8;       // s within 128-chunk
        const int kbt   = sc * 2 + (s_off >> 6);
        const int k_in  = s_off & 63;
        const int gk    = k_in >> 3;
        f16x4 w0, w1;
        #pragma unroll
        for (int j = 0; j < 4; ++j) { w0[j] = T[s_off + j][d]; w1[j] = T[s_off + 4 + j][d]; }
        f16_t* dst = Vt + (((size_t)bh * (S_LEN/BN) + kbt) * D_DIM + d) * 64
                        + ((gk ^ (d & 7)) * 8);
        *(f16x4*)dst = w0;
        *(f16x4*)(dst + 4) = w1;
    }
}

__global__ __launch_bounds__(512, 4)
void fa_fwd(const float* __restrict__ Q, const float* __restrict__ K,
            const float* __restrict__ V, const void* __restrict__ M,
            const u64b* __restrict__ bm, const bf16_t* __restrict__ Kb,
            const f16_t* __restrict__ Vt, float* __restrict__ O)
{
    // separate symbols -> provably disjoint for alias analysis
    __shared__ __align__(16) bf16_t KldsA[BN * D_DIM];
    __shared__ __align__(16) bf16_t KldsB[BN * D_DIM];
    __shared__ __align__(16) f16_t  VldsA[D_DIM * BN];
    __shared__ __align__(16) f16_t  VldsB[D_DIM * BN];

    const int tid  = threadIdx.x;
    const int wave = tid >> 6;        // 0..7
    const int lane = tid & 63;
    const int quad = lane >> 4;
    const int ln   = lane & 15;

    const int bh = blockIdx.x;   // b*16 + h  (x=bh: same-head blocks share XCD
    const int qc = blockIdx.y;   // q chunk 0..7         under RR dispatch)
    const int b  = bh >> 4;
    const int qbase = qc * QCH + wave * 32;   // wave owns 32 q-rows, 2 subtiles

    const size_t head_off = (size_t)bh * S_LEN * D_DIM;
    const float* Qh = Q + head_off;
    const float* Kh = K + head_off;
    const float* Vh = V + head_off;
    const bf16_t* Kbh = Kb ? (Kb + head_off) : nullptr;
    const u8*  Mb8  = (const u8*)M  + (size_t)b * S_LEN * S_LEN;
    const int* Mb32 = (const int*)M + (size_t)b * S_LEN * S_LEN;

    int mask_is_u8 = 0;
    if (!bm) {   // fallback mask-dtype probe
        int probe = ((const int*)M)[(tid * 8179) & ((1 << 21) - 1)];
        mask_is_u8 = __syncthreads_or((unsigned)probe > 1u);
    }

    // ---- Q fragments (B-operand), 2 subtiles: f32 load, *QSCALE, cvt bf16
    bf16x8 qfrag[2][2];
    #pragma unroll
    for (int n = 0; n < 2; ++n) {
        const float* qrow = Qh + (size_t)(qbase + n*16 + ln) * D_DIM;
        #pragma unroll
        for (int s = 0; s < 2; ++s) {
            float4 a = *(const float4*)(qrow + s * 32 + quad * 8);
            float4 c = *(const float4*)(qrow + s * 32 + quad * 8 + 4);
            bf16x8 w;
            w[0]=(bf16_t)(a.x*QSCALE); w[1]=(bf16_t)(a.y*QSCALE);
            w[2]=(bf16_t)(a.z*QSCALE); w[3]=(bf16_t)(a.w*QSCALE);
            w[4]=(bf16_t)(c.x*QSCALE); w[5]=(bf16_t)(c.y*QSCALE);
            w[6]=(bf16_t)(c.z*QSCALE); w[7]=(bf16_t)(c.w*QSCALE);
            qfrag[n][s] = w;
        }
    }

    f32x4 accO[2][4] = {{{0.f,0.f,0.f,0.f},{0.f,0.f,0.f,0.f},
                         {0.f,0.f,0.f,0.f},{0.f,0.f,0.f,0.f}},
                        {{0.f,0.f,0.f,0.f},{0.f,0.f,0.f,0.f},
                         {0.f,0.f,0.f,0.f},{0.f,0.f,0.f,0.f}}};
    float lpart0 = 0.f, lpart1 = 0.f;   // per-lane partial l, subtile 0/1

    // ---- LDS read offsets, precomputed once.  K rows sigma-permuted:
    //   t=2T+u: lane ln loads key row sigma = 32T + (ln>>2)*8 + 4u + (ln&3)
    //   -> read key = fswf(sigma) = (ln&3)|(((ln>>2)&1)<<2)
    const int fswl = (ln & 3) | (((ln >> 2) & 1) << 2);
    const int xv   = ln & 7;             // == d&7 for V reads (d = dt*16+ln)
    int koff[2][4];
    #pragma unroll
    for (int s = 0; s < 2; ++s)
      #pragma unroll
      for (int T = 0; T < 2; ++T)
        #pragma unroll
        for (int u = 0; u < 2; ++u)
            koff[s][2*T+u] = (32*T + (ln >> 2) * 8 + 4*u + (ln & 3)) * D_DIM
                           + (((s*4 + quad) ^ fswl) * 8);
    int voff[2][4];
    #pragma unroll
    for (int T = 0; T < 2; ++T)
      #pragma unroll
      for (int dt = 0; dt < 4; ++dt)
            voff[T][dt] = (dt*16 + ln) * D_DIM + (((T*4 + quad) ^ xv) * 8);

    const size_t bmrow = ((size_t)b * S_LEN + qbase + ln) * 32;

    // roff = 0 or 16 (subtile row offset)
    auto load_wm = [&](int kb, int roff) -> u64b {
        if (bm) return bm[bmrow + (size_t)roff * 32 + (kb >> 6)];
        u64b w = 0;
        if (mask_is_u8) {
            const u8* mp = Mb8 + (size_t)(qbase + roff + ln) * S_LEN + kb;
            #pragma unroll
            for (int t2 = 0; t2 < 2; ++t2)
                #pragma unroll
                for (int j = 0; j < 8; ++j) {
                    const int k = t2*32 + quad*8 + j;
                    if (mp[k]) w |= 1ull << k;
                }
        } else {
            const int* mp = Mb32 + (size_t)(qbase + roff + ln) * S_LEN + kb;
            #pragma unroll
            for (int t2 = 0; t2 < 2; ++t2)
                #pragma unroll
                for (int j = 0; j < 8; ++j) {
                    const int k = t2*32 + quad*8 + j;
                    if (mp[k]) w |= 1ull << k;
                }
        }
        return w;
    };

    // 8 waves stage one 16KB K+V tile: each wave 1KB of K + 1KB of V
    auto prefetch = [&](int kb, bf16_t* Kl, f16_t* Vl) {
        const bf16_t* kt = Kbh + (size_t)kb * D_DIM;
        const f16_t*  vt = Vt + ((size_t)bh * (S_LEN/BN) + (kb >> 6)) * (BN * D_DIM);
        load_lds16(kt + wave * 512 + lane * 8, Kl + wave * 512);
        load_lds16(vt + wave * 512 + lane * 8, Vl + wave * 512);
    };

    auto compute_tile = [&](const bf16_t* Kl, const f16_t* Vl,
                            u64b wm0, u64b wm1) {
        #pragma unroll
        for (int n = 0; n < 2; ++n) {
            const u64b wm = n ? wm1 : wm0;
            // mask folded into accumulator init: masked -> -512 bias,
            // exp2(-512 + s') == 0 exactly.  Bit k of wm == key kb+k.
            // C elem (quad, reg j) of subtile 2T+u <-> key 32T+quad*8+4u+j.
            f32x4 St[4];
            #pragma unroll
            for (int T = 0; T < 2; ++T)
              #pragma unroll
              for (int u = 0; u < 2; ++u) {
                const unsigned nib = (unsigned)(wm >> (T*32 + quad*8 + u*4)) & 0xFu;
                f32x4 iv;
                #pragma unroll
                for (int j = 0; j < 4; ++j)
                    iv[j] = (nib & (1u << j)) ? -512.f : 0.f;
                St[2*T + u] = iv;
              }
            // S^T = K Q^T (exp2 domain): mfma(A=K sigma-permuted, B=Q-frag)
            #pragma unroll
            for (int s = 0; s < 2; ++s)
              #pragma unroll
              for (int t = 0; t < 4; ++t) {
                bf16x8 ak = *(const bf16x8*)(Kl + koff[s][t]);
                St[t] = __builtin_amdgcn_mfma_f32_16x16x32_bf16(
                            ak, qfrag[n][s], St[t], 0, 0, 0);
              }
            // p = exp2(s'); St[2T]||St[2T+1] forms the 16x16x32_f16 A-frag
            // [m=ln(q)][k=quad*8+j] for keys 32T+quad*8+j.
            float lacc = 0.f;
            #pragma unroll
            for (int T = 0; T < 2; ++T) {
                f16x2 h[4];
                #pragma unroll
                for (int u = 0; u < 2; ++u)
                  #pragma unroll
                  for (int jj = 0; jj < 2; ++jj) {
                    const float e0 = __builtin_amdgcn_exp2f(St[2*T+u][2*jj]);
                    const float e1 = __builtin_amdgcn_exp2f(St[2*T+u][2*jj+1]);
                    lacc += e0 + e1;
                    h[u*2+jj] = cvt_pk_f16(e0, e1);
                  }
                const f16x8 pa = {h[0][0], h[0][1], h[1][0], h[1][1],
                                  h[2][0], h[2][1], h[3][0], h[3][1]};
                // O += P V : 16x16x32 f16, B-frags = swizzled b128 from V^T
                #pragma unroll
                for (int dt = 0; dt < 4; ++dt) {
                    f16x8 bv = *(const f16x8*)(Vl + voff[T][dt]);
                    accO[n][dt] = __builtin_amdgcn_mfma_f32_16x16x32_f16(
                                      pa, bv, accO[n][dt], 0, 0, 0);
                }
            }
            if (n) lpart1 += lacc; else lpart0 += lacc;
        }
    };

    if (Kbh) {
        // ---- fast path: async DMA staging, double-buffered, 1 barrier/tile;
        // wm loads pipelined one tile ahead (needed at tile START)
        prefetch(0, KldsA, VldsA);
        u64b wmA0 = load_wm(0, 0), wmA1 = load_wm(0, 16);
        for (int kb = 0; kb < S_LEN; kb += 2 * BN) {
            __syncthreads();                       // tile kb DMA landed
            u64b wmB0 = load_wm(kb + BN, 0);       // always in-bounds
            u64b wmB1 = load_wm(kb + BN, 16);
            if (kb + BN < S_LEN) prefetch(kb + BN, KldsB, VldsB);
            compute_tile(KldsA, VldsA, wmA0, wmA1);
            __syncthreads();                       // tile kb+BN DMA landed
            const int kn = (kb + 2*BN < S_LEN) ? (kb + 2*BN) : 0;  // clamp OOB
            wmA0 = load_wm(kn, 0);
            wmA1 = load_wm(kn, 16);
            if (kb + 2*BN < S_LEN) prefetch(kb + 2*BN, KldsA, VldsA);
            compute_tile(KldsB, VldsB, wmB0, wmB1);
        }
    } else {
        // ---- fallback: in-kernel cvt staging (swizzled), 2 barriers/tile;
        // first 4 waves stage (256 thr), all 8 waves compute.
        const int srow = tid >> 2;
        const int sgrp = tid & 3;
        for (int kb = 0; kb < S_LEN; kb += BN) {
            __syncthreads();
            if (tid < 256) {
                const float* kp = Kh + (size_t)(kb + srow) * D_DIM + sgrp * 16;
                #pragma unroll
                for (int h = 0; h < 2; ++h) {
                    float4 a = *(const float4*)(kp + h * 8);
                    float4 c = *(const float4*)(kp + h * 8 + 4);
                    bf16x8 w;
                    w[0]=(bf16_t)a.x; w[1]=(bf16_t)a.y; w[2]=(bf16_t)a.z; w[3]=(bf16_t)a.w;
                    w[4]=(bf16_t)c.x; w[5]=(bf16_t)c.y; w[6]=(bf16_t)c.z; w[7]=(bf16_t)c.w;
                    const int g = sgrp * 2 + h;
                    *(bf16x8*)&KldsA[srow * D_DIM + ((g ^ fswf(srow)) * 8)] = w;
                }
                const float* vp = Vh + (size_t)(kb + srow) * D_DIM + sgrp * 16;
                float vv[16];
                #pragma unroll
                for (int g = 0; g < 4; ++g) {
                    float4 a = *(const float4*)(vp + g * 4);
                    vv[g*4+0]=a.x; vv[g*4+1]=a.y; vv[g*4+2]=a.z; vv[g*4+3]=a.w;
                }
                const int gk = srow >> 3;
                #pragma unroll
                for (int jj = 0; jj < 16; ++jj) {
                    const int j = (jj + srow) & 15;            // bank derotation
                    const int d = sgrp * 16 + j;
                    VldsA[d * D_DIM + ((gk ^ (d & 7)) * 8) + (srow & 7)] = (f16_t)vv[j];
                }
            }
            __syncthreads();
            compute_tile(KldsA, VldsA, load_wm(kb, 0), load_wm(kb, 16));
        }
    }

    // ---- epilogue: per subtile, reduce l across quads (q=ln), O/l
    #pragma unroll
    for (int n = 0; n < 2; ++n) {
        float lp = n ? lpart1 : lpart0;
        lp += __shfl_xor(lp, 16, 64);
        lp += __shfl_xor(lp, 32, 64);
        #pragma unroll
        for (int r = 0; r < 4; ++r) {
            const float lr  = __shfl(lp, quad * 4 + r, 64);  // lane ln==q
            const float inv = (lr > 0.f) ? 1.f / lr : 0.f;
            float* orow = O + head_off
                        + (size_t)(qbase + n*16 + quad*4 + r) * D_DIM;
            #pragma unroll
            for (int dt = 0; dt < 4; ++dt)
                orow[16*dt + ln] = accO[n][dt][r] * inv;
        }
    }
}

extern "C" void kernel_launch(void* const* d_in, const int* in_sizes, int n_in,
                              void* d_out, int out_size, void* d_ws, size_t ws_size,
                              hipStream_t stream) {
    (void)in_sizes; (void)n_in; (void)out_size;
    const float* Q = (const float*)d_in[0];
    const float* K = (const float*)d_in[1];
    const float* V = (const float*)d_in[2];
    const void*  M = d_in[3];
    float* O = (float*)d_out;

    const size_t bm_bytes = (size_t)2 * S_LEN * (S_LEN / 64) * 8;   // 1 MiB
    const size_t kv_elems = (size_t)BH * S_LEN * D_DIM;             // 4.19M
    const size_t need_all = bm_bytes + 2 * kv_elems * 2;            // +16.8MB

    u64b*   bm = (ws_size >= bm_bytes) ? (u64b*)d_ws : nullptr;
    bf16_t* Kb = nullptr; f16_t* Vt = nullptr;
    if (ws_size >= need_all) {
        Kb = (bf16_t*)((char*)d_ws + bm_bytes);
        Vt = (f16_t*)(Kb + kv_elems);
    }

    if (bm)
        mask_to_bits<<<dim3(131072 / 256), dim3(256), 0, stream>>>(
            (const unsigned*)M, bm);
    if (Kb) {
        k_prep<<<dim3((unsigned)(kv_elems / 8 / 256)), dim3(256), 0, stream>>>(K, Kb);
        v_transpose<<<dim3(S_LEN / 128, BH), dim3(256), 0, stream>>>(V, Vt);
    }

    dim3 grid(BH, S_LEN / QCH);   // (32, 8): x=bh, 256 blocks = 1/CU
    fa_fwd<<<grid, dim3(512), 0, stream>>>(Q, K, V, M, bm, Kb, Vt, O);
}

// Round 7
// 175.986 us; speedup vs baseline: 3.8269x; 3.8269x over previous
//
#include <hip/hip_runtime.h>
#include <hip/hip_bf16.h>

// ScaleDotProduct attention fwd, MI355X gfx950.  B=2 H=16 S=2048 D=64.
// Dtypes (locked r5): Q/K/V f32, output f32, mask u8-or-i32 (runtime probe).
// Flash: one block (4 waves) per 64-row Q tile per (b,h).
//
// r17 = r10 fa_fwd VERBATIM + fused single-launch pre-pass.
// Post-mortem r11-r16: every change to the K-loop timing (PV K=32, mask-to-
// init, 128/256-row tiles, 1-block/CU) collapsed the L2 reuse equilibrium
// that gives r10 its 79MB FETCH / 72us (measured collapses: 185-564us,
// FETCH 197MB-1.06GB).  The equilibrium is timing-self-synchronized 32-
// blocks/head L2 sharing; faster per-tile compute desyncs it.  fa_fwd inner
// loop is therefore FROZEN at r10.  Remaining target: the constant ~112us
// of non-fa_fwd time (r0/r3/r4/r5/r6: 110/117/118/117/109us) vs ~15us of
// actual pre-pass memory work -> launch-gap/serialization dominated ->
// fuse mask_to_bits + k_prep + v_transpose into ONE 512-block kernel.
//
// r10 notes (verified 72us, FETCH 79MB):
//  * S^T orientation: QK^T computed as mfma(A=K,B=Q) -> C-layout lane holds
//    (q=ln, k=quad*4+r) == A-frag layout of mfma_f32_16x16x16f16 ->
//    exp2(S^T) feeds PV DIRECTLY in registers (no P LDS round-trip).
//  * V staged as f16; PV B-frags = swizzled ds_read_b64.
//  * Mask: one u64 bitmask load per lane (row q=ln); l = per-lane partial,
//    reduced once at epilogue (shfl_xor 16/32 + shfl gather).
//  * LDS 32KB -> 4 blocks/CU.
// Layouts (m89/m120-verified + canonical 16x16x16):
//   16x16 C/D: col=lane&15, row=quad*4+reg
//   16x16x32 A: [m=ln][k=quad*8+j]  B: [k=quad*8+j][n=ln]
//   16x16x16 A: [m=ln][k=quad*4+j]  B: [k=quad*4+j][n=ln]
// Fixed-max exp2-domain softmax (r7): p=exp2(s*log2e/8); masked p=0;
// l==0 -> 0 reproduces nan_to_num.

#define S_LEN 2048
#define D_DIM 64
#define BH    32
#define BM    64
#define BN    64
#define PST   72
#define QSCALE 0.1803368801f   // 0.125 * log2(e)

typedef __bf16    bf16_t;
typedef _Float16  f16_t;
typedef bf16_t bf16x8 __attribute__((ext_vector_type(8)));
typedef f16_t  f16x4  __attribute__((ext_vector_type(4)));
typedef float  f32x4  __attribute__((ext_vector_type(4)));
typedef unsigned char  u8;
typedef unsigned long long u64b;

__device__ __forceinline__ void load_lds16(const void* g, void* l) {
    __builtin_amdgcn_global_load_lds(
        (const __attribute__((address_space(1))) void*)g,
        (__attribute__((address_space(3))) void*)l, 16, 0, 0);
}

// ---- standalone mask pre-pass (fallback when only bm workspace fits)
__global__ __launch_bounds__(256)
void mask_to_bits(const unsigned* __restrict__ M, u64b* __restrict__ bm)
{
    const int t = threadIdx.x;
    unsigned p = M[(t * 8179) & ((1 << 21) - 1)];
    const int is_u8 = __syncthreads_or(p > 1u);
    const int id = blockIdx.x * 256 + t;   // u64 index; 131072 total
    u64b w = 0;
    if (is_u8) {
        const uint4* src = (const uint4*)((const u8*)M + (size_t)id * 64);
        #pragma unroll
        for (int g = 0; g < 4; ++g) {
            uint4 x = src[g];
            const unsigned dw[4] = {x.x, x.y, x.z, x.w};
            #pragma unroll
            for (int q = 0; q < 4; ++q) {
                const unsigned v = dw[q];
                const int base = g * 16 + q * 4;
                if (v & 0x000000FFu) w |= 1ull << (base + 0);
                if (v & 0x0000FF00u) w |= 1ull << (base + 1);
                if (v & 0x00FF0000u) w |= 1ull << (base + 2);
                if (v & 0xFF000000u) w |= 1ull << (base + 3);
            }
        }
    } else {
        const uint4* src = (const uint4*)(M + (size_t)id * 64);
        #pragma unroll
        for (int g = 0; g < 16; ++g) {
            uint4 x = src[g];
            if (x.x) w |= 1ull << (g * 4 + 0);
            if (x.y) w |= 1ull << (g * 4 + 1);
            if (x.z) w |= 1ull << (g * 4 + 2);
            if (x.w) w |= 1ull << (g * 4 + 3);
        }
    }
    bm[id] = w;
}

// ---- FUSED pre-pass: mask->bits + K->bf16 swizzled + V->f16 tile images.
// 512 blocks x 256 thr, one launch (replaces 3; kills 2 inter-launch gaps).
__global__ __launch_bounds__(256)
void prepass_all(const unsigned* __restrict__ M, u64b* __restrict__ bm,
                 const float* __restrict__ K, bf16_t* __restrict__ Kb,
                 const float* __restrict__ V, f16_t* __restrict__ Vt)
{
    const int t   = threadIdx.x;
    const int blk = blockIdx.x;           // 0..511

    // -- mask dtype probe (256 shared samples -> uniform per-block verdict)
    unsigned p = M[(t * 8179) & ((1 << 21) - 1)];
    const int is_u8 = __syncthreads_or(p > 1u);

    // -- job 1: mask -> u64 bitmask (131072 words; 1 per thread)
    {
        const int id = blk * 256 + t;
        u64b w = 0;
        if (is_u8) {
            const uint4* src = (const uint4*)((const u8*)M + (size_t)id * 64);
            #pragma unroll
            for (int g = 0; g < 4; ++g) {
                uint4 x = src[g];
                const unsigned dw[4] = {x.x, x.y, x.z, x.w};
                #pragma unroll
                for (int q = 0; q < 4; ++q) {
                    const unsigned v = dw[q];
                    const int base = g * 16 + q * 4;
                    if (v & 0x000000FFu) w |= 1ull << (base + 0);
                    if (v & 0x0000FF00u) w |= 1ull << (base + 1);
                    if (v & 0x00FF0000u) w |= 1ull << (base + 2);
                    if (v & 0xFF000000u) w |= 1ull << (base + 3);
                }
            }
        } else {
            const uint4* src = (const uint4*)(M + (size_t)id * 64);
            #pragma unroll
            for (int g = 0; g < 16; ++g) {
                uint4 x = src[g];
                if (x.x) w |= 1ull << (g * 4 + 0);
                if (x.y) w |= 1ull << (g * 4 + 1);
                if (x.z) w |= 1ull << (g * 4 + 2);
                if (x.w) w |= 1ull << (g * 4 + 3);
            }
        }
        bm[id] = w;
    }

    // -- job 2: K -> bf16, 16B groups XOR-swizzled (r10: g ^ (row&7));
    // 524288 vec8 chunks over 131072 threads = 4 each (grid-stride)
    #pragma unroll
    for (int j = 0; j < 4; ++j) {
        const size_t i = ((size_t)(blk * 256 + t) + (size_t)j * 131072) * 8;
        float4 a = *(const float4*)(K + i);
        float4 b = *(const float4*)(K + i + 4);
        bf16x8 w;
        w[0]=(bf16_t)a.x; w[1]=(bf16_t)a.y; w[2]=(bf16_t)a.z; w[3]=(bf16_t)a.w;
        w[4]=(bf16_t)b.x; w[5]=(bf16_t)b.y; w[6]=(bf16_t)b.z; w[7]=(bf16_t)b.w;
        const size_t r = i >> 6;
        const int    g = (int)((i & 63) >> 3);
        *(bf16x8*)(Kb + r * 64 + ((g ^ (int)(r & 7)) * 8)) = w;
    }

    // -- job 3: V f32 [bh][s][d] -> Vt f16 tile-images
    // [bh][kbt][d][k_in64], 16B-group XOR swizzle (g^(d&7)).
    // block -> (sc = blk&15, bh = blk>>4); identical body to r10 v_transpose.
    {
        __shared__ f16_t T[128][PST];
        const int sc = blk & 15;
        const int bh = blk >> 4;
        const float* Vh = V + ((size_t)bh * S_LEN + sc * 128) * D_DIM;
        #pragma unroll
        for (int it = 0; it < 4; ++it) {
            const int row = it * 32 + (t >> 3);
            const int c8  = (t & 7) * 8;
            float4 a = *(const float4*)(Vh + row * D_DIM + c8);
            float4 b = *(const float4*)(Vh + row * D_DIM + c8 + 4);
            f16_t* d = &T[row][c8];
            d[0]=(f16_t)a.x; d[1]=(f16_t)a.y; d[2]=(f16_t)a.z; d[3]=(f16_t)a.w;
            d[4]=(f16_t)b.x; d[5]=(f16_t)b.y; d[6]=(f16_t)b.z; d[7]=(f16_t)b.w;
        }
        __syncthreads();
        const int d = t >> 2;
        #pragma unroll
        for (int g = 0; g < 4; ++g) {
            const int s_off = (t & 3) * 32 + g * 8;       // s within 128-chunk
            const int kbt   = sc * 2 + (s_off >> 6);
            const int k_in  = s_off & 63;
            const int gk    = k_in >> 3;
            f16x4 w0, w1;
            #pragma unroll
            for (int j = 0; j < 4; ++j) { w0[j] = T[s_off + j][d]; w1[j] = T[s_off + 4 + j][d]; }
            f16_t* dst = Vt + (((size_t)bh * (S_LEN/BN) + kbt) * D_DIM + d) * 64
                            + ((gk ^ (d & 7)) * 8);
            *(f16x4*)dst = w0;
            *(f16x4*)(dst + 4) = w1;
        }
    }
}

__global__ __launch_bounds__(256, 4)
void fa_fwd(const float* __restrict__ Q, const float* __restrict__ K,
            const float* __restrict__ V, const void* __restrict__ M,
            const u64b* __restrict__ bm, const bf16_t* __restrict__ Kb,
            const f16_t* __restrict__ Vt, float* __restrict__ O)
{
    // separate symbols -> provably disjoint for alias analysis
    __shared__ __align__(16) bf16_t KldsA[BN * D_DIM];
    __shared__ __align__(16) bf16_t KldsB[BN * D_DIM];
    __shared__ __align__(16) f16_t  VldsA[D_DIM * BN];
    __shared__ __align__(16) f16_t  VldsB[D_DIM * BN];

    const int tid  = threadIdx.x;
    const int wave = tid >> 6;
    const int lane = tid & 63;
    const int quad = lane >> 4;
    const int ln   = lane & 15;

    const int qt = blockIdx.x;   // q tile (0..31)
    const int bh = blockIdx.y;   // b*16 + h
    const int b  = bh >> 4;
    const int qbase = qt * BM + wave * 16;

    const size_t head_off = (size_t)bh * S_LEN * D_DIM;
    const float* Qh = Q + head_off;
    const float* Kh = K + head_off;
    const float* Vh = V + head_off;
    const bf16_t* Kbh = Kb ? (Kb + head_off) : nullptr;
    const u8*  Mb8  = (const u8*)M  + (size_t)b * S_LEN * S_LEN;
    const int* Mb32 = (const int*)M + (size_t)b * S_LEN * S_LEN;

    int mask_is_u8 = 0;
    if (!bm) {   // fallback mask-dtype probe
        int probe = ((const int*)M)[(tid * 8179) & ((1 << 21) - 1)];
        mask_is_u8 = __syncthreads_or((unsigned)probe > 1u);
    }

    // ---- Q fragments (B-operand): f32 load, *QSCALE, cvt bf16 (once/block)
    bf16x8 qfrag[2];
    {
        const float* qrow = Qh + (size_t)(qbase + ln) * D_DIM;
        #pragma unroll
        for (int s = 0; s < 2; ++s) {
            float4 a = *(const float4*)(qrow + s * 32 + quad * 8);
            float4 c = *(const float4*)(qrow + s * 32 + quad * 8 + 4);
            bf16x8 w;
            w[0]=(bf16_t)(a.x*QSCALE); w[1]=(bf16_t)(a.y*QSCALE);
            w[2]=(bf16_t)(a.z*QSCALE); w[3]=(bf16_t)(a.w*QSCALE);
            w[4]=(bf16_t)(c.x*QSCALE); w[5]=(bf16_t)(c.y*QSCALE);
            w[6]=(bf16_t)(c.z*QSCALE); w[7]=(bf16_t)(c.w*QSCALE);
            qfrag[s] = w;
        }
    }

    f32x4 accO[4] = {{0.f,0.f,0.f,0.f},{0.f,0.f,0.f,0.f},
                     {0.f,0.f,0.f,0.f},{0.f,0.f,0.f,0.f}};
    float lpart = 0.f;   // per-lane partial l for q-row = ln

    const int xg = ln & 7;   // row-derived XOR for swizzled LDS reads
    const size_t bmrow = ((size_t)b * S_LEN + qbase + ln) * 32;

    auto load_wm = [&](int kb) -> u64b {
        if (bm) return bm[bmrow + (kb >> 6)];
        u64b w = 0;
        if (mask_is_u8) {
            const u8* mp = Mb8 + (size_t)(qbase + ln) * S_LEN + kb;
            #pragma unroll
            for (int t = 0; t < 4; ++t)
                #pragma unroll
                for (int j = 0; j < 4; ++j) {
                    const int k = t*16 + quad*4 + j;
                    if (mp[k]) w |= 1ull << k;
                }
        } else {
            const int* mp = Mb32 + (size_t)(qbase + ln) * S_LEN + kb;
            #pragma unroll
            for (int t = 0; t < 4; ++t)
                #pragma unroll
                for (int j = 0; j < 4; ++j) {
                    const int k = t*16 + quad*4 + j;
                    if (mp[k]) w |= 1ull << k;
                }
        }
        return w;
    };

    auto prefetch = [&](int kb, bf16_t* Kl, f16_t* Vl) {
        const bf16_t* kt = Kbh + (size_t)kb * D_DIM;
        const f16_t*  vt = Vt + ((size_t)bh * (S_LEN/BN) + (kb >> 6)) * (BN * D_DIM);
        #pragma unroll
        for (int i = 0; i < 2; ++i) {
            const int c = wave + 4 * i;          // 1KB chunk id (8 per tile)
            load_lds16(kt + c * 512 + lane * 8, Kl + c * 512);
            load_lds16(vt + c * 512 + lane * 8, Vl + c * 512);
        }
    };

    auto compute_tile = [&](const bf16_t* Kl, const f16_t* Vl, u64b wm) {
        // S^T = K Q^T (exp2 domain): mfma(A=K-frag, B=Q-frag)
        f32x4 St[4] = {{0.f,0.f,0.f,0.f},{0.f,0.f,0.f,0.f},
                       {0.f,0.f,0.f,0.f},{0.f,0.f,0.f,0.f}};
        __builtin_amdgcn_s_setprio(1);
        #pragma unroll
        for (int s = 0; s < 2; ++s) {
            #pragma unroll
            for (int t = 0; t < 4; ++t) {
                bf16x8 ak = *(const bf16x8*)
                    &Kl[(16*t + ln) * D_DIM + (((s*4 + quad) ^ xg) * 8)];
                St[t] = __builtin_amdgcn_mfma_f32_16x16x32_bf16(ak, qfrag[s], St[t], 0, 0, 0);
            }
        }
        __builtin_amdgcn_s_setprio(0);
        // p = exp2(s'), masked -> 0; pack to f16 A-frags IN REGISTERS
        f16x4 pa[4];
        #pragma unroll
        for (int t = 0; t < 4; ++t) {
            const unsigned nib = (unsigned)(wm >> (t*16 + quad*4)) & 0xFu;
            #pragma unroll
            for (int j = 0; j < 4; ++j) {
                const float p = (nib & (1u << j)) ? 0.f
                              : __builtin_amdgcn_exp2f(St[t][j]);
                lpart += p;
                pa[t][j] = (f16_t)p;
            }
        }
        // O += P V : 16x16x16 f16, B-frags = swizzled b64 from V^T tile
        __builtin_amdgcn_s_setprio(1);
        #pragma unroll
        for (int t = 0; t < 4; ++t) {
            #pragma unroll
            for (int dt = 0; dt < 4; ++dt) {
                const int g = 2*t + (quad >> 1);
                f16x4 bv = *(const f16x4*)
                    &Vl[(dt*16 + ln) * D_DIM + ((g ^ xg) * 8) + (quad & 1) * 4];
                accO[dt] = __builtin_amdgcn_mfma_f32_16x16x16f16(pa[t], bv, accO[dt], 0, 0, 0);
            }
        }
        __builtin_amdgcn_s_setprio(0);
    };

    if (Kbh) {
        // ---- fast path: async DMA staging, double-buffered, 1 barrier/tile
        prefetch(0, KldsA, VldsA);
        for (int kb = 0; kb < S_LEN; kb += 2 * BN) {
            __syncthreads();                       // tile kb DMA landed
            u64b wm = load_wm(kb);                 // issued before next DMA
            if (kb + BN < S_LEN) prefetch(kb + BN, KldsB, VldsB);
            compute_tile(KldsA, VldsA, wm);
            __syncthreads();                       // tile kb+BN DMA landed
            wm = load_wm(kb + BN);
            if (kb + 2*BN < S_LEN) prefetch(kb + 2*BN, KldsA, VldsA);
            compute_tile(KldsB, VldsB, wm);
        }
    } else {
        // ---- fallback: in-kernel cvt staging (swizzled), 2 barriers/tile
        const int srow = tid >> 2;
        const int sgrp = tid & 3;
        for (int kb = 0; kb < S_LEN; kb += BN) {
            __syncthreads();
            const float* kp = Kh + (size_t)(kb + srow) * D_DIM + sgrp * 16;
            #pragma unroll
            for (int h = 0; h < 2; ++h) {
                float4 a = *(const float4*)(kp + h * 8);
                float4 c = *(const float4*)(kp + h * 8 + 4);
                bf16x8 w;
                w[0]=(bf16_t)a.x; w[1]=(bf16_t)a.y; w[2]=(bf16_t)a.z; w[3]=(bf16_t)a.w;
                w[4]=(bf16_t)c.x; w[5]=(bf16_t)c.y; w[6]=(bf16_t)c.z; w[7]=(bf16_t)c.w;
                const int g = sgrp * 2 + h;
                *(bf16x8*)&KldsA[srow * D_DIM + ((g ^ (srow & 7)) * 8)] = w;
            }
            const float* vp = Vh + (size_t)(kb + srow) * D_DIM + sgrp * 16;
            float vv[16];
            #pragma unroll
            for (int g = 0; g < 4; ++g) {
                float4 a = *(const float4*)(vp + g * 4);
                vv[g*4+0]=a.x; vv[g*4+1]=a.y; vv[g*4+2]=a.z; vv[g*4+3]=a.w;
            }
            const int gk = srow >> 3;
            #pragma unroll
            for (int jj = 0; jj < 16; ++jj) {
                const int j = (jj + srow) & 15;            // bank derotation
                const int d = sgrp * 16 + j;
                VldsA[d * D_DIM + ((gk ^ (d & 7)) * 8) + (srow & 7)] = (f16_t)vv[j];
            }
            __syncthreads();
            compute_tile(KldsA, VldsA, load_wm(kb));
        }
    }

    // ---- epilogue: reduce l across quads (q=ln), gather per-row, O/l
    lpart += __shfl_xor(lpart, 16, 64);
    lpart += __shfl_xor(lpart, 32, 64);
    #pragma unroll
    for (int r = 0; r < 4; ++r) {
        const float lr  = __shfl(lpart, quad * 4 + r, 64);  // lane ln==q==quad*4+r
        const float inv = (lr > 0.f) ? 1.f / lr : 0.f;
        float* orow = O + head_off + (size_t)(qbase + quad*4 + r) * D_DIM;
        #pragma unroll
        for (int dt = 0; dt < 4; ++dt)
            orow[16*dt + ln] = accO[dt][r] * inv;
    }
}

extern "C" void kernel_launch(void* const* d_in, const int* in_sizes, int n_in,
                              void* d_out, int out_size, void* d_ws, size_t ws_size,
                              hipStream_t stream) {
    (void)in_sizes; (void)n_in; (void)out_size;
    const float* Q = (const float*)d_in[0];
    const float* K = (const float*)d_in[1];
    const float* V = (const float*)d_in[2];
    const void*  M = d_in[3];
    float* O = (float*)d_out;

    const size_t bm_bytes = (size_t)2 * S_LEN * (S_LEN / 64) * 8;   // 1 MiB
    const size_t kv_elems = (size_t)BH * S_LEN * D_DIM;             // 4.19M
    const size_t need_all = bm_bytes + 2 * kv_elems * 2;            // +16.8MB

    u64b*   bm = (ws_size >= bm_bytes) ? (u64b*)d_ws : nullptr;
    bf16_t* Kb = nullptr; f16_t* Vt = nullptr;
    if (ws_size >= need_all) {
        Kb = (bf16_t*)((char*)d_ws + bm_bytes);
        Vt = (f16_t*)(Kb + kv_elems);
    }

    if (bm && Kb) {
        // single fused pre-pass launch (replaces 3)
        prepass_all<<<dim3(512), dim3(256), 0, stream>>>(
            (const unsigned*)M, bm, K, Kb, V, Vt);
    } else if (bm) {
        mask_to_bits<<<dim3(131072 / 256), dim3(256), 0, stream>>>(
            (const unsigned*)M, bm);
    }

    dim3 grid(S_LEN / BM, BH);
    fa_fwd<<<grid, dim3(256), 0, stream>>>(Q, K, V, M, bm, Kb, Vt, O);
}